// Round 3
// baseline (576.429 us; speedup 1.0000x reference)
//
#include <hip/hip_runtime.h>

typedef _Float16 f16;
typedef _Float16 f16x8 __attribute__((ext_vector_type(8)));
typedef float f32x16 __attribute__((ext_vector_type(16)));

#define MFMA32(A, B, C) __builtin_amdgcn_mfma_f32_32x32x16_f16((A), (B), (C), 0, 0, 0)

__device__ __forceinline__ float sigm_(float x) {
    return __builtin_amdgcn_rcpf(1.f + __builtin_amdgcn_exp2f(-1.44269504088896f * x));
}
__device__ __forceinline__ float tanh_(float x) {
    float e = __builtin_amdgcn_exp2f(2.88539008177793f * x);   // e^(2x)
    return 1.f - 2.f * __builtin_amdgcn_rcpf(1.f + e);
}

// Convert a row-major fp32 weight W[J][256] into fragment-major f16 for
// v_mfma_f32_32x32x16_f16 B-operand (B[k][j] = W[j][k]):
// idx = ((nt*16 + kt)*64 + lane)*8 + e ;  j = nt*32 + (lane&31), k = kt*16 + (lane>>5)*8 + e
__global__ void frag_conv(const float* __restrict__ W, f16* __restrict__ dst, int total) {
    for (int idx = blockIdx.x * blockDim.x + threadIdx.x; idx < total;
         idx += gridDim.x * blockDim.x) {
        int e  = idx & 7;
        int lp = (idx >> 3) & 63;
        int kt = (idx >> 9) & 15;
        int nt = idx >> 13;
        int j = (nt << 5) + (lp & 31);
        int k = (kt << 4) + ((lp >> 5) << 3) + e;
        dst[idx] = (f16)W[j * 256 + k];
    }
}

// 1 wave/EU minimum: allow the allocator the full register file (live set
// ~185 VGPRs). 128-reg target (compiler default) spilled 93 MB of scratch
// per dispatch and thrashed L2 -> whole kernel was fetch-bound at 2.6 TB/s.
__global__ __launch_bounds__(512, 1)
void lstm_fused(const float* __restrict__ statf,   // [8192][256]
                const float* __restrict__ tfg,     // [8192][24]
                const float* __restrict__ tmg,     // [8192][24]
                const float* __restrict__ h0,      // [8192][256]
                const float* __restrict__ c0,      // [8192][256]
                const float* __restrict__ Wih,     // [1024][2]
                const float* __restrict__ bih,     // [1024]
                const float* __restrict__ bhh,     // [1024]
                const float* __restrict__ b1,
                const float* __restrict__ b2,
                const float* __restrict__ b3,
                const float* __restrict__ Wlr,     // [512]
                const float* __restrict__ blr,     // [1]
                const f16* __restrict__ WBH,       // frag-major W_hh  (32 nt)
                const f16* __restrict__ WB1,       // frag-major W1    (8 nt)
                const f16* __restrict__ WB2,
                const f16* __restrict__ WB3,
                float* __restrict__ out)           // [8193]
{
    // A-fragment layout LDS: Af[buf][kt][lane][e] <-> val[row=lane&31][k=kt*16+(lane>>5)*8+e]
    __shared__ f16   Af[3][16][64][8];   // 48 KB: buf0/1 = h ping-pong, buf2 = static/s
    __shared__ float tf_l[32][24];
    __shared__ float tm_l[32][24];
    __shared__ float wlr_l[512];

    const int tid = threadIdx.x;
    const int w   = tid >> 6;       // wave 0..7
    const int l   = tid & 63;       // lane
    const int b0  = blockIdx.x * 32;

    // ---------------- init fills ----------------
    for (int i = tid; i < 32 * 24; i += 512) {
        int r = i / 24, t = i - r * 24;
        tf_l[r][t] = tfg[(b0 + r) * 24 + t];
        tm_l[r][t] = tmg[(b0 + r) * 24 + t];
    }
    wlr_l[tid] = Wlr[tid];

    // h0 -> Af[0], static -> Af[2]
    for (int i = tid; i < 1024; i += 512) {
        int fr = i >> 6, lp = i & 63;
        int row  = lp & 31;
        int koff = (fr << 4) + ((lp >> 5) << 3);
        const float4* s4 = (const float4*)&h0[(b0 + row) * 256 + koff];
        float4 a = s4[0], b = s4[1];
        f16x8 v;
        v[0]=(f16)a.x; v[1]=(f16)a.y; v[2]=(f16)a.z; v[3]=(f16)a.w;
        v[4]=(f16)b.x; v[5]=(f16)b.y; v[6]=(f16)b.z; v[7]=(f16)b.w;
        *(f16x8*)(&Af[0][fr][lp][0]) = v;
        const float4* t4 = (const float4*)&statf[(b0 + row) * 256 + koff];
        float4 c = t4[0], d = t4[1];
        f16x8 v2;
        v2[0]=(f16)c.x; v2[1]=(f16)c.y; v2[2]=(f16)c.z; v2[3]=(f16)c.w;
        v2[4]=(f16)d.x; v2[5]=(f16)d.y; v2[6]=(f16)d.z; v2[7]=(f16)d.w;
        *(f16x8*)(&Af[2][fr][lp][0]) = v2;
    }

    // ---------------- per-lane constants ----------------
    const int jc = (w << 5) + (l & 31);          // this lane's h-column (0..255)
    float xa[4], xb[4], xc[4];
    #pragma unroll
    for (int g = 0; g < 4; ++g) {
        int jj = (g << 8) + jc;
        xa[g] = Wih[jj * 2];
        xb[g] = Wih[jj * 2 + 1];
        xc[g] = bih[jj] + bhh[jj];
    }
    float cst[16];
    #pragma unroll
    for (int reg = 0; reg < 16; ++reg) {
        int bl = (reg & 3) + ((reg >> 2) << 3) + ((l >> 5) << 2);
        cst[reg] = c0[(b0 + bl) * 256 + jc];
    }

    const int lane8   = l << 3;
    const int wkt     = jc >> 4;                  // kt this lane writes (h scatter)
    const int wlp_hi  = ((l >> 3) & 1) << 5;
    const int we      = l & 7;

    // t-invariant B tiles for kt=0,1: load once, reuse all 24 steps.
    // Covers the post-barrier window at each step start (nothing in flight).
    f16x8 Bp0[4], Bp1[4];
    #pragma unroll
    for (int g = 0; g < 4; ++g) {
        Bp0[g] = *(const f16x8*)(WBH + (((g * 8 + w) * 16 + 0) * 512) + lane8);
        Bp1[g] = *(const f16x8*)(WBH + (((g * 8 + w) * 16 + 1) * 512) + lane8);
    }
    __syncthreads();

    // ---------------- LSTM over 24 steps ----------------
    #pragma unroll 1
    for (int t = 0; t < 24; ++t) {
        const int cur = t & 1;
        f32x16 acc[4];
        #pragma unroll
        for (int g = 0; g < 4; ++g)
            #pragma unroll
            for (int e = 0; e < 16; ++e) acc[g][e] = xc[g];   // fold bias into C

        f16x8 Bf[2][4];
        f16x8 Aq[2];
        Aq[0] = *(const f16x8*)(&Af[cur][0][l][0]);

        // kt=0: uses persistent Bp0; prefetch A(1), B(2)
        Aq[1] = *(const f16x8*)(&Af[cur][1][l][0]);
        #pragma unroll
        for (int g = 0; g < 4; ++g)
            Bf[0][g] = *(const f16x8*)(WBH + (((g * 8 + w) * 16 + 2) * 512) + lane8);
        #pragma unroll
        for (int g = 0; g < 4; ++g) acc[g] = MFMA32(Aq[0], Bp0[g], acc[g]);

        // kt=1: uses persistent Bp1; prefetch A(2), B(3)
        Aq[0] = *(const f16x8*)(&Af[cur][2][l][0]);
        #pragma unroll
        for (int g = 0; g < 4; ++g)
            Bf[1][g] = *(const f16x8*)(WBH + (((g * 8 + w) * 16 + 3) * 512) + lane8);
        #pragma unroll
        for (int g = 0; g < 4; ++g) acc[g] = MFMA32(Aq[1], Bp1[g], acc[g]);

        // kt=2..15: B double-buffered 2 ahead, A 1 ahead
        #pragma unroll
        for (int kt = 2; kt < 16; ++kt) {
            const int cb = kt & 1;
            if (kt < 15)
                Aq[(kt + 1) & 1] = *(const f16x8*)(&Af[cur][kt + 1][l][0]);
            // MFMAs read Bf[cb]; the reload below is WAR-ordered after them
            #pragma unroll
            for (int g = 0; g < 4; ++g)
                acc[g] = MFMA32(Aq[cb], Bf[cb][g], acc[g]);
            if (kt < 14) {
                #pragma unroll
                for (int g = 0; g < 4; ++g)
                    Bf[cb][g] = *(const f16x8*)(WBH + (((g * 8 + w) * 16 + (kt + 2)) * 512) + lane8);
            }
        }

        // epilogue: gates -> (c,h); write h (f16) into other A-frag buffer
        #pragma unroll
        for (int reg = 0; reg < 16; ++reg) {
            const int   bl  = (reg & 3) + ((reg >> 2) << 3) + ((l >> 5) << 2);
            const float tfv = tf_l[bl][t];
            const float tmv = tm_l[bl][t];
            float gi = acc[0][reg] + xa[0] * tfv + xb[0] * tmv;
            float gf = acc[1][reg] + xa[1] * tfv + xb[1] * tmv;
            float gg = acc[2][reg] + xa[2] * tfv + xb[2] * tmv;
            float go = acc[3][reg] + xa[3] * tfv + xb[3] * tmv;
            float i_ = sigm_(gi);
            float f_ = sigm_(gf);
            float g_ = tanh_(gg);
            float o_ = sigm_(go);
            float c_ = f_ * cst[reg] + i_ * g_;
            cst[reg] = c_;
            float h_ = o_ * tanh_(c_);
            Af[cur ^ 1][wkt][bl | wlp_hi][we] = (f16)h_;
        }
        __syncthreads();
    }
    // final h lives in Af[0]

    // ---------------- static MLP: 3 layers, in buf {2,1,2} -> out {1,2,1} ----------------
    {
        const f16*   WBl[3] = {WB1, WB2, WB3};
        const float* bls[3] = {b1, b2, b3};
        #pragma unroll
        for (int layer = 0; layer < 3; ++layer) {
            const int inb  = (layer == 1) ? 1 : 2;
            const int outb = (layer == 1) ? 2 : 1;
            float bias = bls[layer][jc];
            f32x16 acc2;
            #pragma unroll
            for (int e = 0; e < 16; ++e) acc2[e] = bias;

            f16x8 Bq[2], Aq2[2];
            Bq[0]  = *(const f16x8*)(WBl[layer] + ((w * 16 + 0) * 512) + lane8);
            Aq2[0] = *(const f16x8*)(&Af[inb][0][l][0]);
            #pragma unroll
            for (int kt = 0; kt < 16; ++kt) {
                const int cb = kt & 1, nb = cb ^ 1;
                if (kt < 15) {
                    Bq[nb]  = *(const f16x8*)(WBl[layer] + ((w * 16 + (kt + 1)) * 512) + lane8);
                    Aq2[nb] = *(const f16x8*)(&Af[inb][kt + 1][l][0]);
                }
                acc2 = MFMA32(Aq2[cb], Bq[cb], acc2);
            }
            #pragma unroll
            for (int reg = 0; reg < 16; ++reg) {
                float v = acc2[reg];
                v = v > 0.f ? v : 0.f;
                const int bl2 = (reg & 3) + ((reg >> 2) << 3) + ((l >> 5) << 2);
                Af[outb][wkt][bl2 | wlp_hi][we] = (f16)v;
            }
            __syncthreads();
        }
    }

    // ---------------- classifier: predicts = [h, s] . Wlr + blr ----------------
    {
        const int r  = (w << 2) + (l >> 4);     // row 0..31
        const int lg = l & 15;
        const int lp = r | (((lg >> 3) & 1) << 5);
        const int ee = lg & 7;
        float sum = 0.f;
        #pragma unroll
        for (int i = 0; i < 16; ++i) {
            int j = lg + (i << 4);
            float hv = (float)Af[0][i][lp][ee];
            float sv = (float)Af[1][i][lp][ee];
            sum += hv * wlr_l[j] + sv * wlr_l[256 + j];
        }
        sum += __shfl_xor(sum, 8);
        sum += __shfl_xor(sum, 4);
        sum += __shfl_xor(sum, 2);
        sum += __shfl_xor(sum, 1);
        if (lg == 0) out[b0 + r] = sum + blr[0];
    }
}

__global__ __launch_bounds__(1024)
void bce_kernel(const float* __restrict__ pred, const float* __restrict__ tgt,
                float* __restrict__ lossp) {
    const int tid = threadIdx.x;
    float acc = 0.f;
    for (int i = tid; i < 8192; i += 1024) {
        float p  = pred[i];
        float t  = tgt[i];
        float ax = fabsf(p);
        acc += fmaxf(p, 0.f) - p * t
             + log1pf(__builtin_amdgcn_exp2f(-1.44269504088896f * ax));
    }
    #pragma unroll
    for (int m = 32; m >= 1; m >>= 1) acc += __shfl_xor(acc, m);
    __shared__ float red[16];
    if ((tid & 63) == 0) red[tid >> 6] = acc;
    __syncthreads();
    if (tid < 16) {
        float v = red[tid];
        #pragma unroll
        for (int m = 8; m >= 1; m >>= 1) v += __shfl_xor(v, m);
        if (tid == 0) lossp[0] = v * (1.f / 8192.f);
    }
}

extern "C" void kernel_launch(void* const* d_in, const int* in_sizes, int n_in,
                              void* d_out, int out_size, void* d_ws, size_t ws_size,
                              hipStream_t stream) {
    const float* statf = (const float*)d_in[0];
    const float* tfg   = (const float*)d_in[1];
    const float* tmg   = (const float*)d_in[2];
    const float* tgt   = (const float*)d_in[3];
    const float* h0    = (const float*)d_in[4];
    const float* c0    = (const float*)d_in[5];
    const float* Wih   = (const float*)d_in[6];
    const float* Whh   = (const float*)d_in[7];
    const float* bih   = (const float*)d_in[8];
    const float* bhh   = (const float*)d_in[9];
    const float* W1    = (const float*)d_in[10];
    const float* b1    = (const float*)d_in[11];
    const float* W2    = (const float*)d_in[12];
    const float* b2    = (const float*)d_in[13];
    const float* W3    = (const float*)d_in[14];
    const float* b3    = (const float*)d_in[15];
    const float* Wlr   = (const float*)d_in[16];
    const float* blr   = (const float*)d_in[17];
    float* out = (float*)d_out;

    f16* WBH = (f16*)d_ws;            // 262144 halfs
    f16* WB1 = WBH + 262144;          // 65536 halfs each
    f16* WB2 = WB1 + 65536;
    f16* WB3 = WB2 + 65536;

    frag_conv<<<512, 512, 0, stream>>>(Whh, WBH, 262144);
    frag_conv<<<128, 512, 0, stream>>>(W1, WB1, 65536);
    frag_conv<<<128, 512, 0, stream>>>(W2, WB2, 65536);
    frag_conv<<<128, 512, 0, stream>>>(W3, WB3, 65536);

    lstm_fused<<<256, 512, 0, stream>>>(statf, tfg, tmg, h0, c0, Wih, bih, bhh,
                                        b1, b2, b3, Wlr, blr,
                                        WBH, WB1, WB2, WB3, out);

    bce_kernel<<<1, 1024, 0, stream>>>(out, tgt, out + 8192);
}

// Round 4
// 316.858 us; speedup vs baseline: 1.8192x; 1.8192x over previous
//
#include <hip/hip_runtime.h>

typedef _Float16 f16;
typedef _Float16 f16x8 __attribute__((ext_vector_type(8)));
typedef float f32x16 __attribute__((ext_vector_type(16)));

#define MFMA32(A, B, C) __builtin_amdgcn_mfma_f32_32x32x16_f16((A), (B), (C), 0, 0, 0)

__device__ __forceinline__ float sigm_(float x) {
    return __builtin_amdgcn_rcpf(1.f + __builtin_amdgcn_exp2f(-1.44269504088896f * x));
}
__device__ __forceinline__ float tanh_(float x) {
    float e = __builtin_amdgcn_exp2f(2.88539008177793f * x);   // e^(2x)
    return 1.f - 2.f * __builtin_amdgcn_rcpf(1.f + e);
}

// async global->LDS, 16B per lane (dest = wave-uniform base + lane*16)
__device__ __forceinline__ void stage16(const void* g, void* s) {
    __builtin_amdgcn_global_load_lds(
        (const __attribute__((address_space(1))) unsigned int*)(g),
        (__attribute__((address_space(3))) unsigned int*)(s), 16, 0, 0);
}

// ---- W_hh repack, kt-major: dst[((kt*32+nt)*64+lane)*8+e] = W[j][k]
//      j = nt*32+(lane&31), k = kt*16+((lane>>5)<<3)+e
// Each kt-slice (32 KB) is contiguous -> stageable linearly by a whole block.
__global__ void frag_conv_kt(const float* __restrict__ W, f16* __restrict__ dst) {
    int idx = blockIdx.x * blockDim.x + threadIdx.x;   // 512*512 = 262144 exact
    int e  = idx & 7;
    int lp = (idx >> 3) & 63;
    int nt = (idx >> 9) & 31;
    int kt = idx >> 14;
    int j = (nt << 5) + (lp & 31);
    int k = (kt << 4) + ((lp >> 5) << 3) + e;
    dst[idx] = (f16)W[j * 256 + k];
}

// ---- MLP weights keep the old nt-major fragment layout (register path)
__global__ void frag_conv(const float* __restrict__ W, f16* __restrict__ dst, int total) {
    for (int idx = blockIdx.x * blockDim.x + threadIdx.x; idx < total;
         idx += gridDim.x * blockDim.x) {
        int e  = idx & 7;
        int lp = (idx >> 3) & 63;
        int kt = (idx >> 9) & 15;
        int nt = idx >> 13;
        int j = (nt << 5) + (lp & 31);
        int k = (kt << 4) + ((lp >> 5) << 3) + e;
        dst[idx] = (f16)W[j * 256 + k];
    }
}

// Stage slice (KT+2)&15 into PN; read A/B of slice KT from Af/PC; 4 MFMAs.
// Counted vmcnt(4): slice KT's 4 loads (issued 2 phases ago) must have
// landed; slice KT+1's 4 stay in flight. Raw s_barrier (NOT __syncthreads:
// that drains vmcnt(0) and kills the pipeline).
#define STAGE4(PN, SRCOFF) do {                                              \
        const char* _g = sb + (SRCOFF);                                      \
        stage16(_g,         (PN) + st_o        );                            \
        stage16(_g +  8192, (PN) + st_o +  4096);                            \
        stage16(_g + 16384, (PN) + st_o +  8192);                            \
        stage16(_g + 24576, (PN) + st_o + 12288);                            \
    } while (0)

#define PHASE(KT, PC, PN) do {                                               \
        asm volatile("s_waitcnt vmcnt(4)" ::: "memory");                     \
        __builtin_amdgcn_s_barrier();                                        \
        __builtin_amdgcn_sched_barrier(0);                                   \
        STAGE4(PN, (((KT) + 2) & 15) * 32768);                               \
        f16x8 Av  = *(const f16x8*)(&Af[KT][l][0]);                          \
        f16x8 Bv0 = *(const f16x8*)((PC) + ((0 * 8 + w) << 9) + (l << 3));   \
        f16x8 Bv1 = *(const f16x8*)((PC) + ((1 * 8 + w) << 9) + (l << 3));   \
        f16x8 Bv2 = *(const f16x8*)((PC) + ((2 * 8 + w) << 9) + (l << 3));   \
        f16x8 Bv3 = *(const f16x8*)((PC) + ((3 * 8 + w) << 9) + (l << 3));   \
        acc0 = MFMA32(Av, Bv0, acc0);                                        \
        acc1 = MFMA32(Av, Bv1, acc1);                                        \
        acc2 = MFMA32(Av, Bv2, acc2);                                        \
        acc3 = MFMA32(Av, Bv3, acc3);                                        \
    } while (0)

__global__ __launch_bounds__(512)
void lstm_fused(const float* __restrict__ statf,   // [8192][256]
                const float* __restrict__ tfg,     // [8192][24]
                const float* __restrict__ tmg,     // [8192][24]
                const float* __restrict__ h0,      // [8192][256]
                const float* __restrict__ c0,      // [8192][256]
                const float* __restrict__ Wih,     // [1024][2]
                const float* __restrict__ bih,     // [1024]
                const float* __restrict__ bhh,     // [1024]
                const float* __restrict__ b1,
                const float* __restrict__ b2,
                const float* __restrict__ b3,
                const float* __restrict__ Wlr,     // [512]
                const float* __restrict__ blr,     // [1]
                const f16* __restrict__ WBH,       // kt-major W_hh frags (512 KB)
                const f16* __restrict__ WB1,       // nt-major W1 frags
                const f16* __restrict__ WB2,
                const f16* __restrict__ WB3,
                float* __restrict__ out)           // [8193]
{
    // 128 KB LDS total (1 block/CU):
    __shared__ __align__(16) f16 wsl[3][16384];        // 96 KB: 3 W-slice buffers
    __shared__ __align__(16) f16 Af[16][64][8];        // 16 KB: h fragments (single buf)
    __shared__ float tf_l[32][24];                     // 3 KB
    __shared__ float tm_l[32][24];                     // 3 KB
    __shared__ float wlr_l[512];                       // 2 KB
    __shared__ f16   xa_l[1024];                       // 2 KB
    __shared__ f16   xb_l[1024];                       // 2 KB
    __shared__ float xc_l[1024];                       // 4 KB

    const int tid = threadIdx.x;
    const int w   = tid >> 6;       // wave 0..7
    const int l   = tid & 63;       // lane
    const int b0  = blockIdx.x * 32;

    // per-thread staging offsets
    const char* sb  = (const char*)WBH + (w << 10) + (l << 4);  // + w*1KB + lane*16B
    const int   st_o = (w << 9) + (l << 3);                      // f16 elems

    // ---- issue prologue stages ASAP (slices 0,1) ----
    {
        f16* s0 = &wsl[0][0];
        f16* s1 = &wsl[1][0];
        #pragma unroll
        for (int i = 0; i < 4; ++i) stage16(sb + i * 8192,         s0 + st_o + i * 4096);
        #pragma unroll
        for (int i = 0; i < 4; ++i) stage16(sb + 32768 + i * 8192, s1 + st_o + i * 4096);
    }

    // ---------------- init fills ----------------
    for (int i = tid; i < 32 * 24; i += 512) {
        int r = i / 24, t = i - r * 24;
        tf_l[r][t] = tfg[(b0 + r) * 24 + t];
        tm_l[r][t] = tmg[(b0 + r) * 24 + t];
    }
    wlr_l[tid] = Wlr[tid];
    for (int i = tid; i < 1024; i += 512) {
        xa_l[i] = (f16)Wih[2 * i];
        xb_l[i] = (f16)Wih[2 * i + 1];
        xc_l[i] = bih[i] + bhh[i];
    }
    // h0 -> Af
    for (int i = tid; i < 1024; i += 512) {
        int fr = i >> 6, lp = i & 63;
        int row  = lp & 31;
        int koff = (fr << 4) + ((lp >> 5) << 3);
        const float4* s4 = (const float4*)&h0[(b0 + row) * 256 + koff];
        float4 a = s4[0], b = s4[1];
        f16x8 v;
        v[0]=(f16)a.x; v[1]=(f16)a.y; v[2]=(f16)a.z; v[3]=(f16)a.w;
        v[4]=(f16)b.x; v[5]=(f16)b.y; v[6]=(f16)b.z; v[7]=(f16)b.w;
        *(f16x8*)(&Af[fr][lp][0]) = v;
    }

    // per-lane constants
    const int jc = (w << 5) + (l & 31);          // this lane's h/gate column
    float cst[16];
    #pragma unroll
    for (int reg = 0; reg < 16; ++reg) {
        int bl = (reg & 3) + ((reg >> 2) << 3) + ((l >> 5) << 2);
        cst[reg] = c0[(b0 + bl) * 256 + jc];
    }
    const int wkt    = jc >> 4;
    const int wlp_hi = ((l >> 3) & 1) << 5;
    const int we     = l & 7;

    // flush init ds_writes before first phase barrier
    asm volatile("s_waitcnt lgkmcnt(0)" ::: "memory");

    f16* p0 = &wsl[0][0];
    f16* p1 = &wsl[1][0];
    f16* p2 = &wsl[2][0];

    // ---------------- LSTM over 24 steps ----------------
    #pragma unroll 1
    for (int t = 0; t < 24; ++t) {
        f32x16 acc0, acc1, acc2, acc3;
        #pragma unroll
        for (int e = 0; e < 16; ++e) { acc0[e] = 0.f; acc1[e] = 0.f; acc2[e] = 0.f; acc3[e] = 0.f; }

        PHASE(0,  p0, p2);  PHASE(1,  p1, p0);  PHASE(2,  p2, p1);
        PHASE(3,  p0, p2);  PHASE(4,  p1, p0);  PHASE(5,  p2, p1);
        PHASE(6,  p0, p2);  PHASE(7,  p1, p0);  PHASE(8,  p2, p1);
        PHASE(9,  p0, p2);  PHASE(10, p1, p0);  PHASE(11, p2, p1);
        PHASE(12, p0, p2);  PHASE(13, p1, p0);  PHASE(14, p2, p1);
        PHASE(15, p0, p2);

        // all waves done reading Af/slices of this step before h overwrite
        asm volatile("s_waitcnt lgkmcnt(0)" ::: "memory");
        __builtin_amdgcn_s_barrier();
        __builtin_amdgcn_sched_barrier(0);

        // epilogue: gates -> (c,h); write h back into Af
        float xav0 = (float)xa_l[jc],       xav1 = (float)xa_l[256 + jc];
        float xav2 = (float)xa_l[512 + jc], xav3 = (float)xa_l[768 + jc];
        float xbv0 = (float)xb_l[jc],       xbv1 = (float)xb_l[256 + jc];
        float xbv2 = (float)xb_l[512 + jc], xbv3 = (float)xb_l[768 + jc];
        float xcv0 = xc_l[jc],       xcv1 = xc_l[256 + jc];
        float xcv2 = xc_l[512 + jc], xcv3 = xc_l[768 + jc];
        #pragma unroll
        for (int reg = 0; reg < 16; ++reg) {
            const int   bl  = (reg & 3) + ((reg >> 2) << 3) + ((l >> 5) << 2);
            const float tfv = tf_l[bl][t];
            const float tmv = tm_l[bl][t];
            float gi = acc0[reg] + xav0 * tfv + xbv0 * tmv + xcv0;
            float gf = acc1[reg] + xav1 * tfv + xbv1 * tmv + xcv1;
            float gg = acc2[reg] + xav2 * tfv + xbv2 * tmv + xcv2;
            float go = acc3[reg] + xav3 * tfv + xbv3 * tmv + xcv3;
            float i_ = sigm_(gi);
            float f_ = sigm_(gf);
            float g_ = tanh_(gg);
            float o_ = sigm_(go);
            float c_ = f_ * cst[reg] + i_ * g_;
            cst[reg] = c_;
            float h_ = o_ * tanh_(c_);
            Af[wkt][bl | wlp_hi][we] = (f16)h_;
        }
        // flush h writes; made visible by next phase-0 barrier
        asm volatile("s_waitcnt lgkmcnt(0)" ::: "memory");

        // rotate slice buffers (16 % 3 == 1)
        f16* tp = p0; p0 = p1; p1 = p2; p2 = tp;
    }

    // drain stray stages before reusing wsl as MLP buffers
    asm volatile("s_waitcnt vmcnt(0)" ::: "memory");
    __builtin_amdgcn_s_barrier();

    // ---------------- static MLP (register path for W) ----------------
    f16* A2 = &wsl[0][0];      // [kt*64+lp][8]
    f16* A3 = &wsl[0][8192];

    for (int i = tid; i < 1024; i += 512) {
        int fr = i >> 6, lp = i & 63;
        int row  = lp & 31;
        int koff = (fr << 4) + ((lp >> 5) << 3);
        const float4* s4 = (const float4*)&statf[(b0 + row) * 256 + koff];
        float4 a = s4[0], b = s4[1];
        f16x8 v;
        v[0]=(f16)a.x; v[1]=(f16)a.y; v[2]=(f16)a.z; v[3]=(f16)a.w;
        v[4]=(f16)b.x; v[5]=(f16)b.y; v[6]=(f16)b.z; v[7]=(f16)b.w;
        *(f16x8*)(A2 + ((fr << 6) + lp) * 8) = v;
    }
    __syncthreads();

    {
        const f16*   WBl[3]  = {WB1, WB2, WB3};
        const float* bls[3]  = {b1, b2, b3};
        f16*         ains[3] = {A2, A3, A2};
        f16*         aous[3] = {A3, A2, A3};
        const int lane8 = l << 3;
        #pragma unroll 1
        for (int layer = 0; layer < 3; ++layer) {
            const f16* WL  = WBl[layer];
            f16* ain  = ains[layer];
            f16* aout = aous[layer];
            float bias = bls[layer][jc];
            f32x16 acc2;
            #pragma unroll
            for (int e = 0; e < 16; ++e) acc2[e] = bias;

            f16x8 Bq[2], Aq2[2];
            Bq[0]  = *(const f16x8*)(WL + ((w * 16 + 0) * 512) + lane8);
            Aq2[0] = *(const f16x8*)(ain + (0 * 64 + l) * 8);
            #pragma unroll
            for (int kt = 0; kt < 16; ++kt) {
                const int cb = kt & 1, nb = cb ^ 1;
                if (kt < 15) {
                    Bq[nb]  = *(const f16x8*)(WL + ((w * 16 + (kt + 1)) * 512) + lane8);
                    Aq2[nb] = *(const f16x8*)(ain + ((kt + 1) * 64 + l) * 8);
                }
                acc2 = MFMA32(Aq2[cb], Bq[cb], acc2);
            }
            __syncthreads();   // done reading ain before overwriting aout (may alias prev in)
            #pragma unroll
            for (int reg = 0; reg < 16; ++reg) {
                float v = acc2[reg];
                v = v > 0.f ? v : 0.f;
                const int bl2 = (reg & 3) + ((reg >> 2) << 3) + ((l >> 5) << 2);
                aout[(wkt * 64 + (bl2 | wlp_hi)) * 8 + we] = (f16)v;
            }
            __syncthreads();
        }
    }

    // ---------------- classifier: predicts = [h, s3] . Wlr + blr ----------------
    {
        const int r  = (w << 2) + (l >> 4);     // row 0..31
        const int lg = l & 15;
        const int lp = r | (((lg >> 3) & 1) << 5);
        const int ee = lg & 7;
        float sum = 0.f;
        #pragma unroll
        for (int i = 0; i < 16; ++i) {
            int j = lg + (i << 4);
            float hv = (float)Af[i][lp][ee];
            float sv = (float)A3[(i * 64 + lp) * 8 + ee];
            sum += hv * wlr_l[j] + sv * wlr_l[256 + j];
        }
        sum += __shfl_xor(sum, 8);
        sum += __shfl_xor(sum, 4);
        sum += __shfl_xor(sum, 2);
        sum += __shfl_xor(sum, 1);
        if (lg == 0) out[b0 + r] = sum + blr[0];
    }
}

__global__ __launch_bounds__(1024)
void bce_kernel(const float* __restrict__ pred, const float* __restrict__ tgt,
                float* __restrict__ lossp) {
    const int tid = threadIdx.x;
    float acc = 0.f;
    for (int i = tid; i < 8192; i += 1024) {
        float p  = pred[i];
        float t  = tgt[i];
        float ax = fabsf(p);
        acc += fmaxf(p, 0.f) - p * t
             + log1pf(__builtin_amdgcn_exp2f(-1.44269504088896f * ax));
    }
    #pragma unroll
    for (int m = 32; m >= 1; m >>= 1) acc += __shfl_xor(acc, m);
    __shared__ float red[16];
    if ((tid & 63) == 0) red[tid >> 6] = acc;
    __syncthreads();
    if (tid < 16) {
        float v = red[tid];
        #pragma unroll
        for (int m = 8; m >= 1; m >>= 1) v += __shfl_xor(v, m);
        if (tid == 0) lossp[0] = v * (1.f / 8192.f);
    }
}

extern "C" void kernel_launch(void* const* d_in, const int* in_sizes, int n_in,
                              void* d_out, int out_size, void* d_ws, size_t ws_size,
                              hipStream_t stream) {
    const float* statf = (const float*)d_in[0];
    const float* tfg   = (const float*)d_in[1];
    const float* tmg   = (const float*)d_in[2];
    const float* tgt   = (const float*)d_in[3];
    const float* h0    = (const float*)d_in[4];
    const float* c0    = (const float*)d_in[5];
    const float* Wih   = (const float*)d_in[6];
    const float* Whh   = (const float*)d_in[7];
    const float* bih   = (const float*)d_in[8];
    const float* bhh   = (const float*)d_in[9];
    const float* W1    = (const float*)d_in[10];
    const float* b1    = (const float*)d_in[11];
    const float* W2    = (const float*)d_in[12];
    const float* b2    = (const float*)d_in[13];
    const float* W3    = (const float*)d_in[14];
    const float* b3    = (const float*)d_in[15];
    const float* Wlr   = (const float*)d_in[16];
    const float* blr   = (const float*)d_in[17];
    float* out = (float*)d_out;

    f16* WBH = (f16*)d_ws;            // 262144 halfs, kt-major
    f16* WB1 = WBH + 262144;          // 65536 halfs each, nt-major
    f16* WB2 = WB1 + 65536;
    f16* WB3 = WB2 + 65536;

    frag_conv_kt<<<512, 512, 0, stream>>>(Whh, WBH);
    frag_conv<<<128, 512, 0, stream>>>(W1, WB1, 65536);
    frag_conv<<<128, 512, 0, stream>>>(W2, WB2, 65536);
    frag_conv<<<128, 512, 0, stream>>>(W3, WB3, 65536);

    lstm_fused<<<256, 512, 0, stream>>>(statf, tfg, tmg, h0, c0, Wih, bih, bhh,
                                        b1, b2, b3, Wlr, blr,
                                        WBH, WB1, WB2, WB3, out);

    bce_kernel<<<1, 1024, 0, stream>>>(out, tgt, out + 8192);
}